// Round 4
// baseline (7280.728 us; speedup 1.0000x reference)
//
#include <hip/hip_runtime.h>
#include <hip/hip_bf16.h>

#define B_ 256
#define T_ 128
#define D_ 512
#define H_ 1024
#define FC_ 1024
#define A_ 32
#define NWG_ 256

typedef short bf16x8 __attribute__((ext_vector_type(8)));
typedef float f32x4 __attribute__((ext_vector_type(4)));

__device__ __forceinline__ float bf2f(unsigned short u) {
  return __uint_as_float(((unsigned)u) << 16);
}
// round-to-nearest-even fp32 -> bf16
__device__ __forceinline__ unsigned short f2bf(float x) {
  unsigned u = __float_as_uint(x);
  u = u + 0x7fffu + ((u >> 16) & 1u);
  return (unsigned short)(u >> 16);
}
__device__ __forceinline__ void unpack8(uint4 v, float* f) {
  f[0] = bf2f(v.x & 0xffff); f[1] = bf2f(v.x >> 16);
  f[2] = bf2f(v.y & 0xffff); f[3] = bf2f(v.y >> 16);
  f[4] = bf2f(v.z & 0xffff); f[5] = bf2f(v.z >> 16);
  f[6] = bf2f(v.w & 0xffff); f[7] = bf2f(v.w >> 16);
}
__device__ __forceinline__ uint4 pack8(const float* f) {
  uint4 v;
  v.x = (unsigned)f2bf(f[0]) | ((unsigned)f2bf(f[1]) << 16);
  v.y = (unsigned)f2bf(f[2]) | ((unsigned)f2bf(f[3]) << 16);
  v.z = (unsigned)f2bf(f[4]) | ((unsigned)f2bf(f[5]) << 16);
  v.w = (unsigned)f2bf(f[6]) | ((unsigned)f2bf(f[7]) << 16);
  return v;
}

// ------------- dtype probe: bf16 inputs -> flag 0, fp32 inputs -> flag 1 -----
__global__ __launch_bounds__(256) void detect_kernel(
    const unsigned short* __restrict__ obs, int* __restrict__ flag)
{
  __shared__ int cnt;
  if (threadIdx.x == 0) cnt = 0;
  __syncthreads();
  int c = 0;
  for (int i = threadIdx.x; i < 8192; i += 256) {
    unsigned e = (obs[i] >> 7) & 0xffu;  // bf16 exponent field
    if (e >= 0x86u) c++;
  }
  atomicAdd(&cnt, c);
  __syncthreads();
  if (threadIdx.x == 0) *flag = (cnt >= 64) ? 1 : 0;
}

// ------------- canonicalize 14 float tensors to bf16 workspace copies -------
struct CanonArgs {
  const void* src[14];
  unsigned short* dst[14];
  int ofs[15];  // cumulative element offsets (all multiples of 8)
};
__global__ __launch_bounds__(256) void canon_kernel(CanonArgs a,
                                                    const int* __restrict__ flag)
{
  const int fl = *flag;
  const int i0 = (blockIdx.x * 256 + threadIdx.x) * 8;
  int t = 0;
  while (t < 14 && i0 >= a.ofs[t + 1]) t++;
  if (t >= 14) return;
  const int local = i0 - a.ofs[t];
  unsigned short* d = a.dst[t] + local;
  if (fl) {
    const float* s = (const float*)a.src[t] + local;
    #pragma unroll
    for (int e = 0; e < 8; e++) d[e] = f2bf(s[e]);
  } else {
    const unsigned short* s = (const unsigned short*)a.src[t] + local;
    #pragma unroll
    for (int e = 0; e < 8; e++) d[e] = s[e];
  }
}

// ---------------- LayerNorm: one wave per row of D=512 (chunked over t) ------
__global__ __launch_bounds__(256) void ln_kernel(
    const void* __restrict__ obs,
    const unsigned short* __restrict__ gamma_,
    const unsigned short* __restrict__ beta_,
    unsigned short* __restrict__ xn, int t0, int tcShift,
    const int* __restrict__ flag)
{
  const int fl = *flag;
  const int lane = threadIdx.x & 63;
  const int rloc = blockIdx.x * 4 + (threadIdx.x >> 6);
  const int b  = rloc >> tcShift;
  const int tl = rloc & ((1 << tcShift) - 1);
  const int grow = b * T_ + t0 + tl;
  float f[8];
  if (fl) {
    const float* of = (const float*)obs + (size_t)grow * D_ + lane * 8;
    const float4 v0 = *(const float4*)of;
    const float4 v1 = *(const float4*)(of + 4);
    f[0] = v0.x; f[1] = v0.y; f[2] = v0.z; f[3] = v0.w;
    f[4] = v1.x; f[5] = v1.y; f[6] = v1.z; f[7] = v1.w;
  } else {
    uint4 v = *(const uint4*)((const unsigned short*)obs + (size_t)grow * D_ + lane * 8);
    unpack8(v, f);
  }
  float s = 0.f, ss = 0.f;
  #pragma unroll
  for (int i = 0; i < 8; i++) { s += f[i]; ss += f[i] * f[i]; }
  #pragma unroll
  for (int off = 32; off > 0; off >>= 1) {
    s  += __shfl_xor(s,  off, 64);
    ss += __shfl_xor(ss, off, 64);
  }
  const float mu  = s * (1.0f / D_);
  const float var = ss * (1.0f / D_) - mu * mu;
  const float inv = rsqrtf(var + 1e-5f);
  float g[8], b8[8];
  unpack8(*(const uint4*)(gamma_ + lane * 8), g);
  unpack8(*(const uint4*)(beta_  + lane * 8), b8);
  float o[8];
  #pragma unroll
  for (int i = 0; i < 8; i++) o[i] = (f[i] - mu) * inv * g[i] + b8[i];
  *(uint4*)(xn + (size_t)rloc * D_ + lane * 8) = pack8(o);
}

// ------------- generic TN GEMM: C[M,N] = A[M,K] * B[N,K]^T + bias -------------
__global__ __launch_bounds__(256) void gemm_tn(
    const unsigned short* __restrict__ A, const unsigned short* __restrict__ Bm,
    const unsigned short* __restrict__ bias, unsigned short* __restrict__ C,
    int M, int N, int K, int relu)
{
  __shared__ short As[128][40];
  __shared__ short Bs[128][40];
  const int tid  = threadIdx.x;
  const int wave = tid >> 6, lane = tid & 63;
  const int quad = lane >> 4, l15 = lane & 15;
  const int m0 = blockIdx.y * 128, n0 = blockIdx.x * 128;
  const int wm = (wave >> 1) * 64, wn = (wave & 1) * 64;
  const int lrow = tid >> 2, lk = (tid & 3) * 8;
  f32x4 acc[4][4] = {};
  const size_t a0 = (size_t)(m0 + lrow) * K + lk;
  const size_t a1 = (size_t)(m0 + lrow + 64) * K + lk;
  const size_t b0 = (size_t)(n0 + lrow) * K + lk;
  const size_t b1 = (size_t)(n0 + lrow + 64) * K + lk;
  for (int k0 = 0; k0 < K; k0 += 32) {
    __syncthreads();
    *(uint4*)&As[lrow][lk]      = *(const uint4*)(A  + a0 + k0);
    *(uint4*)&As[lrow + 64][lk] = *(const uint4*)(A  + a1 + k0);
    *(uint4*)&Bs[lrow][lk]      = *(const uint4*)(Bm + b0 + k0);
    *(uint4*)&Bs[lrow + 64][lk] = *(const uint4*)(Bm + b1 + k0);
    __syncthreads();
    bf16x8 af[4], bfv[4];
    #pragma unroll
    for (int i = 0; i < 4; i++) af[i]  = *(const bf16x8*)&As[wm + i * 16 + l15][quad * 8];
    #pragma unroll
    for (int j = 0; j < 4; j++) bfv[j] = *(const bf16x8*)&Bs[wn + j * 16 + l15][quad * 8];
    #pragma unroll
    for (int i = 0; i < 4; i++)
      #pragma unroll
      for (int j = 0; j < 4; j++)
        acc[i][j] = __builtin_amdgcn_mfma_f32_16x16x32_bf16(af[i], bfv[j], acc[i][j], 0, 0, 0);
  }
  #pragma unroll
  for (int j = 0; j < 4; j++) {
    const int col = n0 + wn + j * 16 + l15;
    const float bj = bias ? bf2f(bias[col]) : 0.0f;
    #pragma unroll
    for (int i = 0; i < 4; i++) {
      const int row = m0 + wm + i * 16 + quad * 4;
      #pragma unroll
      for (int r = 0; r < 4; r++) {
        float v = acc[i][j][r] + bj;
        if (relu) v = fmaxf(v, 0.0f);
        C[(size_t)(row + r) * N + col] = f2bf(v);
      }
    }
  }
}

// ---------------- persistent GRU scan ----------------------------------------
// Grid: exactly 256 WGs x 256 thr (1 per CU; LDS 117KB forces 1 WG/CU so all
// are co-resident). WG (bb,jb): bb = wg>>6 (64 batches), jb = wg&63 (16 cols,
// all 3 gates). W_hh slice (96KB) loaded to LDS ONCE for all Tc steps.
// h master fp32 in-place (each slot touched only by its owner wave); bf16
// mirror double-buffered (A-operand for MFMA), so one grid barrier per step.
__device__ __forceinline__ void grid_barrier(int* cnt, int* gen, int my) {
  __syncthreads();
  if (threadIdx.x == 0) {
    __threadfence();  // release h writes device-wide (cross-XCD)
    int old = __hip_atomic_fetch_add(cnt, 1, __ATOMIC_ACQ_REL, __HIP_MEMORY_SCOPE_AGENT);
    if (old == NWG_ - 1) {
      __hip_atomic_store(cnt, 0, __ATOMIC_RELAXED, __HIP_MEMORY_SCOPE_AGENT);
      __hip_atomic_store(gen, my, __ATOMIC_RELEASE, __HIP_MEMORY_SCOPE_AGENT);
    } else {
      while (__hip_atomic_load(gen, __ATOMIC_ACQUIRE, __HIP_MEMORY_SCOPE_AGENT) < my)
        __builtin_amdgcn_s_sleep(2);
    }
    __threadfence();  // acquire: invalidate caches before reading others' h
  }
  __syncthreads();
}

__global__ __launch_bounds__(256, 1) void gru_scan(
    const unsigned short* __restrict__ xg,   // chunk-local [B][Tc][3H]
    const int* __restrict__ starts,
    const unsigned short* __restrict__ Whh,
    const unsigned short* __restrict__ bhh,
    float* __restrict__ hf,                  // [B][H] fp32 master (in-place)
    unsigned short* __restrict__ hb0,        // bf16 mirror ping
    unsigned short* __restrict__ hb1,        // bf16 mirror pong
    unsigned short* __restrict__ hall,       // [B][Tc][H] bf16
    int t0, int Tc,
    int* __restrict__ bar_cnt, int* __restrict__ bar_gen)
{
  __shared__ short Ws[3 * 16 * 1032];  // [g][jj][k], row stride 1032 (pad)
  __shared__ short Hs[64 * 136];       // [row][k-chunk 128], stride 136 (pad)
  __shared__ float keepv[64];
  const int tid  = threadIdx.x;
  const int wg   = blockIdx.x;
  const int jb   = wg & 63, bb = wg >> 6;
  const int j0   = jb * 16, b0 = bb * 64;
  const int wave = tid >> 6, lane = tid & 63;
  const int quad = lane >> 4, l15 = lane & 15;

  // one-time: W_hh slice -> LDS (48 rows x 1024 k)
  for (int c = tid; c < 48 * 128; c += 256) {
    const int row = c >> 7;          // g*16 + jj
    const int kc  = (c & 127) * 8;
    const int g = row >> 4, jj = row & 15;
    *(uint4*)&Ws[row * 1032 + kc] =
        *(const uint4*)(Whh + (size_t)(g * H_ + j0 + jj) * H_ + kc);
  }
  const float br = bf2f(bhh[j0 + l15]);
  const float bz = bf2f(bhh[H_ + j0 + l15]);
  const float bn = bf2f(bhh[2 * H_ + j0 + l15]);
  const int col = j0 + l15;

  for (int tl = 0; tl < Tc; tl++) {
    const int t = t0 + tl;
    const unsigned short* hin = (t & 1) ? hb1 : hb0;
    unsigned short*      hout = (t & 1) ? hb0 : hb1;
    if (tid < 64) keepv[tid] = starts[(b0 + tid) * T_ + t] ? 0.0f : 1.0f;

    f32x4 acc[3] = {};
    for (int kc0 = 0; kc0 < H_; kc0 += 128) {
      __syncthreads();  // Hs reuse + keepv visibility (first iter)
      #pragma unroll
      for (int c = tid; c < 1024; c += 256) {
        const int row = c >> 4;
        const int kc  = (c & 15) * 8;
        uint4 v = *(const uint4*)(hin + (size_t)(b0 + row) * H_ + kc0 + kc);
        if (keepv[row] == 0.0f) { v.x = 0; v.y = 0; v.z = 0; v.w = 0; }
        *(uint4*)&Hs[row * 136 + kc] = v;
      }
      __syncthreads();
      #pragma unroll
      for (int kk = 0; kk < 128; kk += 32) {
        bf16x8 a = *(const bf16x8*)&Hs[(wave * 16 + l15) * 136 + kk + quad * 8];
        #pragma unroll
        for (int g = 0; g < 3; g++) {
          bf16x8 b = *(const bf16x8*)&Ws[(g * 16 + l15) * 1032 + kc0 + kk + quad * 8];
          acc[g] = __builtin_amdgcn_mfma_f32_16x16x32_bf16(a, b, acc[g], 0, 0, 0);
        }
      }
    }

    // epilogue: rows b0 + wave*16 + quad*4 + r, col j0 + l15
    #pragma unroll
    for (int r = 0; r < 4; r++) {
      const int lrow = wave * 16 + quad * 4 + r;
      const int b = b0 + lrow;
      const float kb = keepv[lrow];
      const size_t xrow = ((size_t)b * Tc + tl) * (3 * H_);
      const float hr = acc[0][r] + br;
      const float hz = acc[1][r] + bz;
      const float hn = acc[2][r] + bn;
      const float xr  = bf2f(xg[xrow + col]);
      const float xz  = bf2f(xg[xrow + H_ + col]);
      const float xnv = bf2f(xg[xrow + 2 * H_ + col]);
      const float rg = 1.0f / (1.0f + __expf(-(xr + hr)));
      const float zg = 1.0f / (1.0f + __expf(-(xz + hz)));
      const float ng = tanhf(xnv + rg * hn);
      const float hm = hf[(size_t)b * H_ + col] * kb;
      const float hv = (1.0f - zg) * ng + zg * hm;
      hf[(size_t)b * H_ + col] = hv;
      const unsigned short hvb = f2bf(hv);
      hout[(size_t)b * H_ + col] = hvb;
      hall[((size_t)b * Tc + tl) * H_ + col] = hvb;
    }
    grid_barrier(bar_cnt, bar_gen, t0 + tl + 1);
  }
}

// ------------- heads: means & log_std fused (N=64), dual-dtype store ---------
__global__ __launch_bounds__(256) void heads_kernel(
    const unsigned short* __restrict__ feats,
    const unsigned short* __restrict__ Wm, const unsigned short* __restrict__ bm,
    const unsigned short* __restrict__ Wl, const unsigned short* __restrict__ bl,
    void* __restrict__ outbuf, int t0, int tcShift, const int* __restrict__ flag)
{
  __shared__ short Fs[64][40];
  __shared__ short Ws[64][40];
  const int fl = *flag;
  const int tid  = threadIdx.x;
  const int wave = tid >> 6, lane = tid & 63;
  const int quad = lane >> 4, l15 = lane & 15;
  const int m0 = blockIdx.x * 64;
  const int lrow = tid >> 2, lk = (tid & 3) * 8;
  f32x4 acc[4] = {};
  for (int k0 = 0; k0 < H_; k0 += 32) {
    __syncthreads();
    *(uint4*)&Fs[lrow][lk] = *(const uint4*)(feats + (size_t)(m0 + lrow) * H_ + k0 + lk);
    const unsigned short* wsrc = (lrow < 32)
        ? (Wm + (size_t)lrow * H_ + k0 + lk)
        : (Wl + (size_t)(lrow - 32) * H_ + k0 + lk);
    *(uint4*)&Ws[lrow][lk] = *(const uint4*)wsrc;
    __syncthreads();
    bf16x8 af = *(const bf16x8*)&Fs[wave * 16 + l15][quad * 8];
    #pragma unroll
    for (int j = 0; j < 4; j++) {
      bf16x8 bfv = *(const bf16x8*)&Ws[j * 16 + l15][quad * 8];
      acc[j] = __builtin_amdgcn_mfma_f32_16x16x32_bf16(af, bfv, acc[j], 0, 0, 0);
    }
  }
  const int tcMask = (1 << tcShift) - 1;
  const size_t lstdBase = (size_t)B_ * T_ * A_;
  #pragma unroll
  for (int j = 0; j < 4; j++) {
    const int col = j * 16 + l15;
    #pragma unroll
    for (int r = 0; r < 4; r++) {
      const int row = m0 + wave * 16 + quad * 4 + r;  // chunk-local
      const int grow = (row >> tcShift) * T_ + t0 + (row & tcMask);
      float v = acc[j][r];
      size_t idx;
      if (col < 32) {
        v += bf2f(bm[col]);
        idx = (size_t)grow * A_ + col;
      } else {
        v += bf2f(bl[col - 32]);
        v = fminf(fmaxf(v, -20.0f), 2.0f);
        idx = lstdBase + (size_t)grow * A_ + (col - 32);
      }
      if (fl) ((float*)outbuf)[idx] = v;
      else    ((unsigned short*)outbuf)[idx] = f2bf(v);
    }
  }
}

__global__ __launch_bounds__(256) void h0_cast(const void* __restrict__ h0,
                                               float* __restrict__ hf,
                                               unsigned short* __restrict__ hb0,
                                               const int* __restrict__ flag) {
  const int fl = *flag;
  int i = blockIdx.x * 256 + threadIdx.x;
  float v = fl ? ((const float*)h0)[i] : bf2f(((const unsigned short*)h0)[i]);
  hf[i] = v;
  hb0[i] = f2bf(v);
}
__global__ __launch_bounds__(256) void hfin_store(const float* __restrict__ h,
                                                  void* __restrict__ outbuf,
                                                  const int* __restrict__ flag) {
  const int fl = *flag;
  const size_t base = 2ull * B_ * T_ * A_;
  int i = blockIdx.x * 256 + threadIdx.x;
  if (fl) ((float*)outbuf)[base + i] = h[i];
  else    ((unsigned short*)outbuf)[base + i] = f2bf(h[i]);
}

extern "C" void kernel_launch(void* const* d_in, const int* in_sizes, int n_in,
                              void* d_out, int out_size, void* d_ws, size_t ws_size,
                              hipStream_t stream)
{
  const void* obs    = d_in[0];
  const void* h0in   = d_in[1];
  const int*  starts = (const int*)d_in[2];
  const void* fsrc[14] = { d_in[5], d_in[7], d_in[9], d_in[11], d_in[13], d_in[15],
                           d_in[3], d_in[4], d_in[6], d_in[8], d_in[10], d_in[12],
                           d_in[14], d_in[16] };
  const int fn[14] = { FC_ * D_, 3 * H_ * FC_, 3 * H_ * H_, H_ * H_, A_ * H_, A_ * H_,
                       D_, D_, FC_, 3 * H_, 3 * H_, H_, A_, A_ };

  char* ws = (char*)d_ws;
  int* flag = (int*)ws;
  size_t cur = 256;
  unsigned short* cdst[14];
  for (int i = 0; i < 14; i++) {
    cdst[i] = (unsigned short*)(ws + cur);
    cur += (size_t)fn[i] * 2;
    cur = (cur + 255) & ~255ull;
  }
  const size_t chunkBase = cur;
  const size_t fixedTail = 1048576ull /*hf*/ + 2ull * 524288ull /*hb0/1*/ + 4096ull /*bar*/;

  // Pick largest Tc with: chunkBase + Tc*2883584 + fixedTail <= ws_size
  int Tc = 1;
  for (int c = 32; c >= 1; c >>= 1) {
    size_t need = chunkBase + (size_t)c * 2883584ull + fixedTail;
    if (need <= ws_size) { Tc = c; break; }
  }
  int tcShift = 0;
  while ((1 << tcShift) < Tc) tcShift++;

  unsigned short* xn   = (unsigned short*)(ws + chunkBase);
  unsigned short* xfc  = (unsigned short*)(ws + chunkBase + (size_t)Tc * 262144ull);
  unsigned short* xg   = (unsigned short*)(ws + chunkBase + (size_t)Tc * 786432ull);
  unsigned short* hall = (unsigned short*)(ws + chunkBase + (size_t)Tc * 2359296ull);
  size_t o = chunkBase + (size_t)Tc * 2883584ull;
  float* hf           = (float*)(ws + o);           o += 1048576ull;
  unsigned short* hb0 = (unsigned short*)(ws + o);  o += 524288ull;
  unsigned short* hb1 = (unsigned short*)(ws + o);  o += 524288ull;
  int* bar            = (int*)(ws + o);             // [0]=cnt [1]=gen
  unsigned short* feats = xg;  // xg dead once the chunk's scan is done

  const unsigned short *Wfc = cdst[0], *Wih = cdst[1], *Whh = cdst[2], *Wout = cdst[3];
  const unsigned short *Wmean = cdst[4], *Wls = cdst[5];
  const unsigned short *gam = cdst[6], *bet = cdst[7], *bfc = cdst[8], *bih = cdst[9];
  const unsigned short *bhh = cdst[10], *bout = cdst[11], *bmean = cdst[12], *bls = cdst[13];

  detect_kernel<<<dim3(1), dim3(256), 0, stream>>>((const unsigned short*)obs, flag);
  CanonArgs ca;
  int total = 0;
  for (int i = 0; i < 14; i++) {
    ca.src[i] = fsrc[i];
    ca.dst[i] = cdst[i];
    ca.ofs[i] = total;
    total += fn[i];
  }
  ca.ofs[14] = total;
  canon_kernel<<<dim3((total / 8 + 255) / 256), dim3(256), 0, stream>>>(ca, flag);
  h0_cast<<<dim3(B_ * H_ / 256), dim3(256), 0, stream>>>(h0in, hf, hb0, flag);
  hipMemsetAsync(bar, 0, 64, stream);

  const int Mc = B_ * Tc;
  for (int t0 = 0; t0 < T_; t0 += Tc) {
    ln_kernel<<<dim3(Mc / 4), dim3(256), 0, stream>>>(obs, gam, bet, xn, t0, tcShift, flag);
    gemm_tn<<<dim3(FC_ / 128, Mc / 128), dim3(256), 0, stream>>>(
        xn, Wfc, bfc, xfc, Mc, FC_, D_, 1);
    gemm_tn<<<dim3(3 * H_ / 128, Mc / 128), dim3(256), 0, stream>>>(
        xfc, Wih, bih, xg, Mc, 3 * H_, FC_, 0);

    gru_scan<<<dim3(NWG_), dim3(256), 0, stream>>>(
        xg, starts, Whh, bhh, hf, hb0, hb1, hall, t0, Tc, bar, bar + 1);

    gemm_tn<<<dim3(H_ / 128, Mc / 128), dim3(256), 0, stream>>>(
        hall, Wout, bout, feats, Mc, H_, H_, 1);
    heads_kernel<<<dim3(Mc / 64), dim3(256), 0, stream>>>(
        feats, Wmean, bmean, Wls, bls, d_out, t0, tcShift, flag);
  }

  hfin_store<<<dim3(B_ * H_ / 256), dim3(256), 0, stream>>>(hf, d_out, flag);
}

// Round 5
// 5395.999 us; speedup vs baseline: 1.3493x; 1.3493x over previous
//
#include <hip/hip_runtime.h>
#include <hip/hip_bf16.h>

#define B_ 256
#define T_ 128
#define D_ 512
#define H_ 1024
#define FC_ 1024
#define A_ 32
#define NWG_ 256

typedef short bf16x8 __attribute__((ext_vector_type(8)));
typedef float f32x4 __attribute__((ext_vector_type(4)));

__device__ __forceinline__ float bf2f(unsigned short u) {
  return __uint_as_float(((unsigned)u) << 16);
}
// round-to-nearest-even fp32 -> bf16
__device__ __forceinline__ unsigned short f2bf(float x) {
  unsigned u = __float_as_uint(x);
  u = u + 0x7fffu + ((u >> 16) & 1u);
  return (unsigned short)(u >> 16);
}
__device__ __forceinline__ void unpack8(uint4 v, float* f) {
  f[0] = bf2f(v.x & 0xffff); f[1] = bf2f(v.x >> 16);
  f[2] = bf2f(v.y & 0xffff); f[3] = bf2f(v.y >> 16);
  f[4] = bf2f(v.z & 0xffff); f[5] = bf2f(v.z >> 16);
  f[6] = bf2f(v.w & 0xffff); f[7] = bf2f(v.w >> 16);
}
__device__ __forceinline__ uint4 pack8(const float* f) {
  uint4 v;
  v.x = (unsigned)f2bf(f[0]) | ((unsigned)f2bf(f[1]) << 16);
  v.y = (unsigned)f2bf(f[2]) | ((unsigned)f2bf(f[3]) << 16);
  v.z = (unsigned)f2bf(f[4]) | ((unsigned)f2bf(f[5]) << 16);
  v.w = (unsigned)f2bf(f[6]) | ((unsigned)f2bf(f[7]) << 16);
  return v;
}

// ------------- dtype probe: bf16 inputs -> flag 0, fp32 inputs -> flag 1 -----
__global__ __launch_bounds__(256) void detect_kernel(
    const unsigned short* __restrict__ obs, int* __restrict__ flag)
{
  __shared__ int cnt;
  if (threadIdx.x == 0) cnt = 0;
  __syncthreads();
  int c = 0;
  for (int i = threadIdx.x; i < 8192; i += 256) {
    unsigned e = (obs[i] >> 7) & 0xffu;  // bf16 exponent field
    if (e >= 0x86u) c++;
  }
  atomicAdd(&cnt, c);
  __syncthreads();
  if (threadIdx.x == 0) *flag = (cnt >= 64) ? 1 : 0;
}

// ------------- canonicalize 14 float tensors to bf16 workspace copies -------
struct CanonArgs {
  const void* src[14];
  unsigned short* dst[14];
  int ofs[15];  // cumulative element offsets (all multiples of 8)
};
__global__ __launch_bounds__(256) void canon_kernel(CanonArgs a,
                                                    const int* __restrict__ flag)
{
  const int fl = *flag;
  const int i0 = (blockIdx.x * 256 + threadIdx.x) * 8;
  int t = 0;
  while (t < 14 && i0 >= a.ofs[t + 1]) t++;
  if (t >= 14) return;
  const int local = i0 - a.ofs[t];
  unsigned short* d = a.dst[t] + local;
  if (fl) {
    const float* s = (const float*)a.src[t] + local;
    #pragma unroll
    for (int e = 0; e < 8; e++) d[e] = f2bf(s[e]);
  } else {
    const unsigned short* s = (const unsigned short*)a.src[t] + local;
    #pragma unroll
    for (int e = 0; e < 8; e++) d[e] = s[e];
  }
}

// ---------------- LayerNorm: one wave per row of D=512 (chunked over t) ------
__global__ __launch_bounds__(256) void ln_kernel(
    const void* __restrict__ obs,
    const unsigned short* __restrict__ gamma_,
    const unsigned short* __restrict__ beta_,
    unsigned short* __restrict__ xn, int t0, int tcShift,
    const int* __restrict__ flag)
{
  const int fl = *flag;
  const int lane = threadIdx.x & 63;
  const int rloc = blockIdx.x * 4 + (threadIdx.x >> 6);
  const int b  = rloc >> tcShift;
  const int tl = rloc & ((1 << tcShift) - 1);
  const int grow = b * T_ + t0 + tl;
  float f[8];
  if (fl) {
    const float* of = (const float*)obs + (size_t)grow * D_ + lane * 8;
    const float4 v0 = *(const float4*)of;
    const float4 v1 = *(const float4*)(of + 4);
    f[0] = v0.x; f[1] = v0.y; f[2] = v0.z; f[3] = v0.w;
    f[4] = v1.x; f[5] = v1.y; f[6] = v1.z; f[7] = v1.w;
  } else {
    uint4 v = *(const uint4*)((const unsigned short*)obs + (size_t)grow * D_ + lane * 8);
    unpack8(v, f);
  }
  float s = 0.f, ss = 0.f;
  #pragma unroll
  for (int i = 0; i < 8; i++) { s += f[i]; ss += f[i] * f[i]; }
  #pragma unroll
  for (int off = 32; off > 0; off >>= 1) {
    s  += __shfl_xor(s,  off, 64);
    ss += __shfl_xor(ss, off, 64);
  }
  const float mu  = s * (1.0f / D_);
  const float var = ss * (1.0f / D_) - mu * mu;
  const float inv = rsqrtf(var + 1e-5f);
  float g[8], b8[8];
  unpack8(*(const uint4*)(gamma_ + lane * 8), g);
  unpack8(*(const uint4*)(beta_  + lane * 8), b8);
  float o[8];
  #pragma unroll
  for (int i = 0; i < 8; i++) o[i] = (f[i] - mu) * inv * g[i] + b8[i];
  *(uint4*)(xn + (size_t)rloc * D_ + lane * 8) = pack8(o);
}

// ------------- generic TN GEMM: C[M,N] = A[M,K] * B[N,K]^T + bias -------------
__global__ __launch_bounds__(256) void gemm_tn(
    const unsigned short* __restrict__ A, const unsigned short* __restrict__ Bm,
    const unsigned short* __restrict__ bias, unsigned short* __restrict__ C,
    int M, int N, int K, int relu)
{
  __shared__ short As[128][40];
  __shared__ short Bs[128][40];
  const int tid  = threadIdx.x;
  const int wave = tid >> 6, lane = tid & 63;
  const int quad = lane >> 4, l15 = lane & 15;
  const int m0 = blockIdx.y * 128, n0 = blockIdx.x * 128;
  const int wm = (wave >> 1) * 64, wn = (wave & 1) * 64;
  const int lrow = tid >> 2, lk = (tid & 3) * 8;
  f32x4 acc[4][4] = {};
  const size_t a0 = (size_t)(m0 + lrow) * K + lk;
  const size_t a1 = (size_t)(m0 + lrow + 64) * K + lk;
  const size_t b0 = (size_t)(n0 + lrow) * K + lk;
  const size_t b1 = (size_t)(n0 + lrow + 64) * K + lk;
  for (int k0 = 0; k0 < K; k0 += 32) {
    __syncthreads();
    *(uint4*)&As[lrow][lk]      = *(const uint4*)(A  + a0 + k0);
    *(uint4*)&As[lrow + 64][lk] = *(const uint4*)(A  + a1 + k0);
    *(uint4*)&Bs[lrow][lk]      = *(const uint4*)(Bm + b0 + k0);
    *(uint4*)&Bs[lrow + 64][lk] = *(const uint4*)(Bm + b1 + k0);
    __syncthreads();
    bf16x8 af[4], bfv[4];
    #pragma unroll
    for (int i = 0; i < 4; i++) af[i]  = *(const bf16x8*)&As[wm + i * 16 + l15][quad * 8];
    #pragma unroll
    for (int j = 0; j < 4; j++) bfv[j] = *(const bf16x8*)&Bs[wn + j * 16 + l15][quad * 8];
    #pragma unroll
    for (int i = 0; i < 4; i++)
      #pragma unroll
      for (int j = 0; j < 4; j++)
        acc[i][j] = __builtin_amdgcn_mfma_f32_16x16x32_bf16(af[i], bfv[j], acc[i][j], 0, 0, 0);
  }
  #pragma unroll
  for (int j = 0; j < 4; j++) {
    const int col = n0 + wn + j * 16 + l15;
    const float bj = bias ? bf2f(bias[col]) : 0.0f;
    #pragma unroll
    for (int i = 0; i < 4; i++) {
      const int row = m0 + wm + i * 16 + quad * 4;
      #pragma unroll
      for (int r = 0; r < 4; r++) {
        float v = acc[i][j][r] + bj;
        if (relu) v = fmaxf(v, 0.0f);
        C[(size_t)(row + r) * N + col] = f2bf(v);
      }
    }
  }
}

// ---------------- persistent GRU scan ----------------------------------------
// 256 WGs (1/CU, LDS-forced). WG = (bb,jb): bb = wg>>6 owns 64 batches, jb =
// wg&63 owns 16 cols x 3 gates. W_hh slice (96KB) + starts bitmask in LDS once.
// h fp32 lives in REGISTERS (4 per thread, owner-stable across steps); bf16
// mirror double-buffered in global for the MFMA A-operand broadcast.
// Sync: only the 64 WGs sharing bb communicate -> per-group flag-array barrier
// (store + parallel poll; no RMW contention).
__global__ __launch_bounds__(256, 1) void gru_scan(
    const unsigned short* __restrict__ xg,   // chunk-local [B][Tc][3H]
    const int* __restrict__ starts,
    const unsigned short* __restrict__ Whh,
    const unsigned short* __restrict__ bhh,
    float* __restrict__ hf,                  // [B][H] fp32 master
    unsigned short* __restrict__ hb0,        // bf16 mirror ping
    unsigned short* __restrict__ hb1,        // bf16 mirror pong
    unsigned short* __restrict__ hall,       // [B][Tc][H] bf16
    int t0, int Tc,
    int* __restrict__ flags)                 // [NWG_] step flags, 64B stride
{
  __shared__ short Ws[3 * 16 * 1032];   // 99 KB: [g][jj][k] stride 1032
  __shared__ short Hs[64 * 136];        // 17 KB: [row][k-chunk 128] stride 136
  __shared__ unsigned sbits[64][4];     // starts bitmask: 64 rows x 128 bits
  const int tid  = threadIdx.x;
  const int wg   = blockIdx.x;
  const int jb   = wg & 63, bb = wg >> 6;
  const int j0   = jb * 16, b0 = bb * 64;
  const int wave = tid >> 6, lane = tid & 63;
  const int quad = lane >> 4, l15 = lane & 15;

  // one-time: W_hh slice -> LDS (48 rows x 1024 k)
  for (int c = tid; c < 48 * 128; c += 256) {
    const int row = c >> 7;          // g*16 + jj
    const int kc  = (c & 127) * 8;
    const int g = row >> 4, jj = row & 15;
    *(uint4*)&Ws[row * 1032 + kc] =
        *(const uint4*)(Whh + (size_t)(g * H_ + j0 + jj) * H_ + kc);
  }
  // one-time: starts -> bitmask
  for (int c = tid; c < 64 * 4; c += 256) {
    const int row = c >> 2, w = c & 3;
    unsigned m = 0;
    #pragma unroll
    for (int bi = 0; bi < 32; bi++)
      m |= (starts[(b0 + row) * T_ + w * 32 + bi] ? 1u : 0u) << bi;
    sbits[row][w] = m;
  }
  const float br = bf2f(bhh[j0 + l15]);
  const float bz = bf2f(bhh[H_ + l15 + j0]);
  const float bn = bf2f(bhh[2 * H_ + j0 + l15]);
  const int col = j0 + l15;

  // register-resident fp32 h: 4 owned slots (rows r0..r0+3, col)
  const int r0 = wave * 16 + quad * 4;
  float hreg[4];
  #pragma unroll
  for (int r = 0; r < 4; r++)
    hreg[r] = hf[(size_t)(b0 + r0 + r) * H_ + col];

  __syncthreads();  // Ws / sbits ready

  for (int tl = 0; tl < Tc; tl++) {
    const int t = t0 + tl;
    const unsigned short* hin = (t & 1) ? hb1 : hb0;
    unsigned short*      hout = (t & 1) ? hb0 : hb1;

    // prefetch this step's xg values (12 scalar loads, consumed in epilogue)
    float xr[4], xz[4], xnv[4];
    #pragma unroll
    for (int r = 0; r < 4; r++) {
      const size_t xrow = ((size_t)(b0 + r0 + r) * Tc + tl) * (3 * H_);
      xr[r]  = bf2f(xg[xrow + col]);
      xz[r]  = bf2f(xg[xrow + H_ + col]);
      xnv[r] = bf2f(xg[xrow + 2 * H_ + col]);
    }

    // prefetch Hs chunk 0 into registers
    uint4 pf[4];
    #pragma unroll
    for (int u = 0; u < 4; u++) {
      const int c = tid + u * 256;
      const int row = c >> 4, kc = (c & 15) * 8;
      pf[u] = *(const uint4*)(hin + (size_t)(b0 + row) * H_ + kc);
    }

    f32x4 acc[3] = {};
    const unsigned tw = (unsigned)(t >> 5), tb = (unsigned)(t & 31);
    for (int kc0 = 0; kc0 < H_; kc0 += 128) {
      __syncthreads();  // Hs consumed by previous iteration's MFMA
      #pragma unroll
      for (int u = 0; u < 4; u++) {
        const int c = tid + u * 256;
        const int row = c >> 4, kc = (c & 15) * 8;
        uint4 v = pf[u];
        if ((sbits[row][tw] >> tb) & 1u) { v.x = 0; v.y = 0; v.z = 0; v.w = 0; }
        *(uint4*)&Hs[row * 136 + kc] = v;
      }
      __syncthreads();
      if (kc0 + 128 < H_) {
        #pragma unroll
        for (int u = 0; u < 4; u++) {
          const int c = tid + u * 256;
          const int row = c >> 4, kc = (c & 15) * 8;
          pf[u] = *(const uint4*)(hin + (size_t)(b0 + row) * H_ + kc0 + 128 + kc);
        }
      }
      #pragma unroll
      for (int kk = 0; kk < 128; kk += 32) {
        bf16x8 a = *(const bf16x8*)&Hs[(wave * 16 + l15) * 136 + kk + quad * 8];
        #pragma unroll
        for (int g = 0; g < 3; g++) {
          bf16x8 b = *(const bf16x8*)&Ws[(g * 16 + l15) * 1032 + kc0 + kk + quad * 8];
          acc[g] = __builtin_amdgcn_mfma_f32_16x16x32_bf16(a, b, acc[g], 0, 0, 0);
        }
      }
    }

    // epilogue: pure registers
    #pragma unroll
    for (int r = 0; r < 4; r++) {
      const int lrow = r0 + r;
      const int b = b0 + lrow;
      const float kb = ((sbits[lrow][tw] >> tb) & 1u) ? 0.0f : 1.0f;
      const float hr = acc[0][r] + br;
      const float hz = acc[1][r] + bz;
      const float hn = acc[2][r] + bn;
      const float rg = 1.0f / (1.0f + __expf(-(xr[r] + hr)));
      const float zg = 1.0f / (1.0f + __expf(-(xz[r] + hz)));
      const float ng = tanhf(xnv[r] + rg * hn);
      const float hv = (1.0f - zg) * ng + zg * (hreg[r] * kb);
      hreg[r] = hv;
      const unsigned short hvb = f2bf(hv);
      hout[(size_t)b * H_ + col] = hvb;
      hall[((size_t)b * Tc + tl) * H_ + col] = hvb;
    }

    // group-local barrier: 64 WGs sharing bb; store + parallel poll (no RMW)
    const int my = t0 + tl + 1;
    __syncthreads();
    if (tid == 0) {
      __threadfence();  // release hout/hall writes device-wide
      __hip_atomic_store(&flags[wg * 16], my, __ATOMIC_RELEASE,
                         __HIP_MEMORY_SCOPE_AGENT);
    }
    if (tid < 64) {
      while (__hip_atomic_load(&flags[(bb * 64 + tid) * 16], __ATOMIC_RELAXED,
                               __HIP_MEMORY_SCOPE_AGENT) < my)
        __builtin_amdgcn_s_sleep(1);
    }
    __syncthreads();
    __threadfence();  // acquire: invalidate before reading peers' hout
  }

  // write back register h to fp32 master
  #pragma unroll
  for (int r = 0; r < 4; r++)
    hf[(size_t)(b0 + r0 + r) * H_ + col] = hreg[r];
}

// ------------- heads: means & log_std fused (N=64), dual-dtype store ---------
__global__ __launch_bounds__(256) void heads_kernel(
    const unsigned short* __restrict__ feats,
    const unsigned short* __restrict__ Wm, const unsigned short* __restrict__ bm,
    const unsigned short* __restrict__ Wl, const unsigned short* __restrict__ bl,
    void* __restrict__ outbuf, int t0, int tcShift, const int* __restrict__ flag)
{
  __shared__ short Fs[64][40];
  __shared__ short Ws[64][40];
  const int fl = *flag;
  const int tid  = threadIdx.x;
  const int wave = tid >> 6, lane = tid & 63;
  const int quad = lane >> 4, l15 = lane & 15;
  const int m0 = blockIdx.x * 64;
  const int lrow = tid >> 2, lk = (tid & 3) * 8;
  f32x4 acc[4] = {};
  for (int k0 = 0; k0 < H_; k0 += 32) {
    __syncthreads();
    *(uint4*)&Fs[lrow][lk] = *(const uint4*)(feats + (size_t)(m0 + lrow) * H_ + k0 + lk);
    const unsigned short* wsrc = (lrow < 32)
        ? (Wm + (size_t)lrow * H_ + k0 + lk)
        : (Wl + (size_t)(lrow - 32) * H_ + k0 + lk);
    *(uint4*)&Ws[lrow][lk] = *(const uint4*)wsrc;
    __syncthreads();
    bf16x8 af = *(const bf16x8*)&Fs[wave * 16 + l15][quad * 8];
    #pragma unroll
    for (int j = 0; j < 4; j++) {
      bf16x8 bfv = *(const bf16x8*)&Ws[j * 16 + l15][quad * 8];
      acc[j] = __builtin_amdgcn_mfma_f32_16x16x32_bf16(af, bfv, acc[j], 0, 0, 0);
    }
  }
  const int tcMask = (1 << tcShift) - 1;
  const size_t lstdBase = (size_t)B_ * T_ * A_;
  #pragma unroll
  for (int j = 0; j < 4; j++) {
    const int col = j * 16 + l15;
    #pragma unroll
    for (int r = 0; r < 4; r++) {
      const int row = m0 + wave * 16 + quad * 4 + r;  // chunk-local
      const int grow = (row >> tcShift) * T_ + t0 + (row & tcMask);
      float v = acc[j][r];
      size_t idx;
      if (col < 32) {
        v += bf2f(bm[col]);
        idx = (size_t)grow * A_ + col;
      } else {
        v += bf2f(bl[col - 32]);
        v = fminf(fmaxf(v, -20.0f), 2.0f);
        idx = lstdBase + (size_t)grow * A_ + (col - 32);
      }
      if (fl) ((float*)outbuf)[idx] = v;
      else    ((unsigned short*)outbuf)[idx] = f2bf(v);
    }
  }
}

__global__ __launch_bounds__(256) void h0_cast(const void* __restrict__ h0,
                                               float* __restrict__ hf,
                                               unsigned short* __restrict__ hb0,
                                               const int* __restrict__ flag) {
  const int fl = *flag;
  int i = blockIdx.x * 256 + threadIdx.x;
  float v = fl ? ((const float*)h0)[i] : bf2f(((const unsigned short*)h0)[i]);
  hf[i] = v;
  hb0[i] = f2bf(v);
}
__global__ __launch_bounds__(256) void hfin_store(const float* __restrict__ h,
                                                  void* __restrict__ outbuf,
                                                  const int* __restrict__ flag) {
  const int fl = *flag;
  const size_t base = 2ull * B_ * T_ * A_;
  int i = blockIdx.x * 256 + threadIdx.x;
  if (fl) ((float*)outbuf)[base + i] = h[i];
  else    ((unsigned short*)outbuf)[base + i] = f2bf(h[i]);
}

extern "C" void kernel_launch(void* const* d_in, const int* in_sizes, int n_in,
                              void* d_out, int out_size, void* d_ws, size_t ws_size,
                              hipStream_t stream)
{
  const void* obs    = d_in[0];
  const void* h0in   = d_in[1];
  const int*  starts = (const int*)d_in[2];
  const void* fsrc[14] = { d_in[5], d_in[7], d_in[9], d_in[11], d_in[13], d_in[15],
                           d_in[3], d_in[4], d_in[6], d_in[8], d_in[10], d_in[12],
                           d_in[14], d_in[16] };
  const int fn[14] = { FC_ * D_, 3 * H_ * FC_, 3 * H_ * H_, H_ * H_, A_ * H_, A_ * H_,
                       D_, D_, FC_, 3 * H_, 3 * H_, H_, A_, A_ };

  char* ws = (char*)d_ws;
  int* flag = (int*)ws;
  size_t cur = 256;
  unsigned short* cdst[14];
  for (int i = 0; i < 14; i++) {
    cdst[i] = (unsigned short*)(ws + cur);
    cur += (size_t)fn[i] * 2;
    cur = (cur + 255) & ~255ull;
  }
  const size_t chunkBase = cur;
  const size_t fixedTail = 1048576ull /*hf*/ + 2ull * 524288ull /*hb0/1*/
                         + 16384ull /*flags*/;

  // Pick largest Tc with: chunkBase + Tc*2883584 + fixedTail <= ws_size
  int Tc = 1;
  for (int c = 32; c >= 1; c >>= 1) {
    size_t need = chunkBase + (size_t)c * 2883584ull + fixedTail;
    if (need <= ws_size) { Tc = c; break; }
  }
  int tcShift = 0;
  while ((1 << tcShift) < Tc) tcShift++;

  unsigned short* xn   = (unsigned short*)(ws + chunkBase);
  unsigned short* xfc  = (unsigned short*)(ws + chunkBase + (size_t)Tc * 262144ull);
  unsigned short* xg   = (unsigned short*)(ws + chunkBase + (size_t)Tc * 786432ull);
  unsigned short* hall = (unsigned short*)(ws + chunkBase + (size_t)Tc * 2359296ull);
  size_t o = chunkBase + (size_t)Tc * 2883584ull;
  float* hf           = (float*)(ws + o);           o += 1048576ull;
  unsigned short* hb0 = (unsigned short*)(ws + o);  o += 524288ull;
  unsigned short* hb1 = (unsigned short*)(ws + o);  o += 524288ull;
  int* flags          = (int*)(ws + o);             // NWG_ x 64B
  unsigned short* feats = xg;  // xg dead once the chunk's scan is done

  const unsigned short *Wfc = cdst[0], *Wih = cdst[1], *Whh = cdst[2], *Wout = cdst[3];
  const unsigned short *Wmean = cdst[4], *Wls = cdst[5];
  const unsigned short *gam = cdst[6], *bet = cdst[7], *bfc = cdst[8], *bih = cdst[9];
  const unsigned short *bhh = cdst[10], *bout = cdst[11], *bmean = cdst[12], *bls = cdst[13];

  detect_kernel<<<dim3(1), dim3(256), 0, stream>>>((const unsigned short*)obs, flag);
  CanonArgs ca;
  int total = 0;
  for (int i = 0; i < 14; i++) {
    ca.src[i] = fsrc[i];
    ca.dst[i] = cdst[i];
    ca.ofs[i] = total;
    total += fn[i];
  }
  ca.ofs[14] = total;
  canon_kernel<<<dim3((total / 8 + 255) / 256), dim3(256), 0, stream>>>(ca, flag);
  h0_cast<<<dim3(B_ * H_ / 256), dim3(256), 0, stream>>>(h0in, hf, hb0, flag);
  hipMemsetAsync(flags, 0, 16384, stream);

  const int Mc = B_ * Tc;
  for (int t0 = 0; t0 < T_; t0 += Tc) {
    ln_kernel<<<dim3(Mc / 4), dim3(256), 0, stream>>>(obs, gam, bet, xn, t0, tcShift, flag);
    gemm_tn<<<dim3(FC_ / 128, Mc / 128), dim3(256), 0, stream>>>(
        xn, Wfc, bfc, xfc, Mc, FC_, D_, 1);
    gemm_tn<<<dim3(3 * H_ / 128, Mc / 128), dim3(256), 0, stream>>>(
        xfc, Wih, bih, xg, Mc, 3 * H_, FC_, 0);

    gru_scan<<<dim3(NWG_), dim3(256), 0, stream>>>(
        xg, starts, Whh, bhh, hf, hb0, hb1, hall, t0, Tc, flags);

    gemm_tn<<<dim3(H_ / 128, Mc / 128), dim3(256), 0, stream>>>(
        hall, Wout, bout, feats, Mc, H_, H_, 1);
    heads_kernel<<<dim3(Mc / 64), dim3(256), 0, stream>>>(
        feats, Wmean, bmean, Wls, bls, d_out, t0, tcShift, flag);
  }

  hfin_store<<<dim3(B_ * H_ / 256), dim3(256), 0, stream>>>(hf, d_out, flag);
}

// Round 6
// 1887.283 us; speedup vs baseline: 3.8578x; 2.8591x over previous
//
#include <hip/hip_runtime.h>
#include <hip/hip_bf16.h>

#define B_ 256
#define T_ 128
#define D_ 512
#define H_ 1024
#define FC_ 1024
#define A_ 32
#define NWG_ 256

typedef short bf16x8 __attribute__((ext_vector_type(8)));
typedef float f32x4 __attribute__((ext_vector_type(4)));

__device__ __forceinline__ float bf2f(unsigned short u) {
  return __uint_as_float(((unsigned)u) << 16);
}
// round-to-nearest-even fp32 -> bf16
__device__ __forceinline__ unsigned short f2bf(float x) {
  unsigned u = __float_as_uint(x);
  u = u + 0x7fffu + ((u >> 16) & 1u);
  return (unsigned short)(u >> 16);
}
__device__ __forceinline__ void unpack8(uint4 v, float* f) {
  f[0] = bf2f(v.x & 0xffff); f[1] = bf2f(v.x >> 16);
  f[2] = bf2f(v.y & 0xffff); f[3] = bf2f(v.y >> 16);
  f[4] = bf2f(v.z & 0xffff); f[5] = bf2f(v.z >> 16);
  f[6] = bf2f(v.w & 0xffff); f[7] = bf2f(v.w >> 16);
}
__device__ __forceinline__ uint4 pack8(const float* f) {
  uint4 v;
  v.x = (unsigned)f2bf(f[0]) | ((unsigned)f2bf(f[1]) << 16);
  v.y = (unsigned)f2bf(f[2]) | ((unsigned)f2bf(f[3]) << 16);
  v.z = (unsigned)f2bf(f[4]) | ((unsigned)f2bf(f[5]) << 16);
  v.w = (unsigned)f2bf(f[6]) | ((unsigned)f2bf(f[7]) << 16);
  return v;
}

// ------------- dtype probe: bf16 inputs -> flag 0, fp32 inputs -> flag 1 -----
__global__ __launch_bounds__(256) void detect_kernel(
    const unsigned short* __restrict__ obs, int* __restrict__ flag)
{
  __shared__ int cnt;
  if (threadIdx.x == 0) cnt = 0;
  __syncthreads();
  int c = 0;
  for (int i = threadIdx.x; i < 8192; i += 256) {
    unsigned e = (obs[i] >> 7) & 0xffu;  // bf16 exponent field
    if (e >= 0x86u) c++;
  }
  atomicAdd(&cnt, c);
  __syncthreads();
  if (threadIdx.x == 0) *flag = (cnt >= 64) ? 1 : 0;
}

// ------------- canonicalize 14 float tensors to bf16 workspace copies -------
struct CanonArgs {
  const void* src[14];
  unsigned short* dst[14];
  int ofs[15];  // cumulative element offsets (all multiples of 8)
};
__global__ __launch_bounds__(256) void canon_kernel(CanonArgs a,
                                                    const int* __restrict__ flag)
{
  const int fl = *flag;
  const int i0 = (blockIdx.x * 256 + threadIdx.x) * 8;
  int t = 0;
  while (t < 14 && i0 >= a.ofs[t + 1]) t++;
  if (t >= 14) return;
  const int local = i0 - a.ofs[t];
  unsigned short* d = a.dst[t] + local;
  if (fl) {
    const float* s = (const float*)a.src[t] + local;
    #pragma unroll
    for (int e = 0; e < 8; e++) d[e] = f2bf(s[e]);
  } else {
    const unsigned short* s = (const unsigned short*)a.src[t] + local;
    #pragma unroll
    for (int e = 0; e < 8; e++) d[e] = s[e];
  }
}

// ---------------- LayerNorm: one wave per row of D=512 (chunked over t) ------
__global__ __launch_bounds__(256) void ln_kernel(
    const void* __restrict__ obs,
    const unsigned short* __restrict__ gamma_,
    const unsigned short* __restrict__ beta_,
    unsigned short* __restrict__ xn, int t0, int tcShift,
    const int* __restrict__ flag)
{
  const int fl = *flag;
  const int lane = threadIdx.x & 63;
  const int rloc = blockIdx.x * 4 + (threadIdx.x >> 6);
  const int b  = rloc >> tcShift;
  const int tl = rloc & ((1 << tcShift) - 1);
  const int grow = b * T_ + t0 + tl;
  float f[8];
  if (fl) {
    const float* of = (const float*)obs + (size_t)grow * D_ + lane * 8;
    const float4 v0 = *(const float4*)of;
    const float4 v1 = *(const float4*)(of + 4);
    f[0] = v0.x; f[1] = v0.y; f[2] = v0.z; f[3] = v0.w;
    f[4] = v1.x; f[5] = v1.y; f[6] = v1.z; f[7] = v1.w;
  } else {
    uint4 v = *(const uint4*)((const unsigned short*)obs + (size_t)grow * D_ + lane * 8);
    unpack8(v, f);
  }
  float s = 0.f, ss = 0.f;
  #pragma unroll
  for (int i = 0; i < 8; i++) { s += f[i]; ss += f[i] * f[i]; }
  #pragma unroll
  for (int off = 32; off > 0; off >>= 1) {
    s  += __shfl_xor(s,  off, 64);
    ss += __shfl_xor(ss, off, 64);
  }
  const float mu  = s * (1.0f / D_);
  const float var = ss * (1.0f / D_) - mu * mu;
  const float inv = rsqrtf(var + 1e-5f);
  float g[8], b8[8];
  unpack8(*(const uint4*)(gamma_ + lane * 8), g);
  unpack8(*(const uint4*)(beta_  + lane * 8), b8);
  float o[8];
  #pragma unroll
  for (int i = 0; i < 8; i++) o[i] = (f[i] - mu) * inv * g[i] + b8[i];
  *(uint4*)(xn + (size_t)rloc * D_ + lane * 8) = pack8(o);
}

// ------------- generic TN GEMM: C[M,N] = A[M,K] * B[N,K]^T + bias -------------
__global__ __launch_bounds__(256) void gemm_tn(
    const unsigned short* __restrict__ A, const unsigned short* __restrict__ Bm,
    const unsigned short* __restrict__ bias, unsigned short* __restrict__ C,
    int M, int N, int K, int relu)
{
  __shared__ short As[128][40];
  __shared__ short Bs[128][40];
  const int tid  = threadIdx.x;
  const int wave = tid >> 6, lane = tid & 63;
  const int quad = lane >> 4, l15 = lane & 15;
  const int m0 = blockIdx.y * 128, n0 = blockIdx.x * 128;
  const int wm = (wave >> 1) * 64, wn = (wave & 1) * 64;
  const int lrow = tid >> 2, lk = (tid & 3) * 8;
  f32x4 acc[4][4] = {};
  const size_t a0 = (size_t)(m0 + lrow) * K + lk;
  const size_t a1 = (size_t)(m0 + lrow + 64) * K + lk;
  const size_t b0 = (size_t)(n0 + lrow) * K + lk;
  const size_t b1 = (size_t)(n0 + lrow + 64) * K + lk;
  for (int k0 = 0; k0 < K; k0 += 32) {
    __syncthreads();
    *(uint4*)&As[lrow][lk]      = *(const uint4*)(A  + a0 + k0);
    *(uint4*)&As[lrow + 64][lk] = *(const uint4*)(A  + a1 + k0);
    *(uint4*)&Bs[lrow][lk]      = *(const uint4*)(Bm + b0 + k0);
    *(uint4*)&Bs[lrow + 64][lk] = *(const uint4*)(Bm + b1 + k0);
    __syncthreads();
    bf16x8 af[4], bfv[4];
    #pragma unroll
    for (int i = 0; i < 4; i++) af[i]  = *(const bf16x8*)&As[wm + i * 16 + l15][quad * 8];
    #pragma unroll
    for (int j = 0; j < 4; j++) bfv[j] = *(const bf16x8*)&Bs[wn + j * 16 + l15][quad * 8];
    #pragma unroll
    for (int i = 0; i < 4; i++)
      #pragma unroll
      for (int j = 0; j < 4; j++)
        acc[i][j] = __builtin_amdgcn_mfma_f32_16x16x32_bf16(af[i], bfv[j], acc[i][j], 0, 0, 0);
  }
  #pragma unroll
  for (int j = 0; j < 4; j++) {
    const int col = n0 + wn + j * 16 + l15;
    const float bj = bias ? bf2f(bias[col]) : 0.0f;
    #pragma unroll
    for (int i = 0; i < 4; i++) {
      const int row = m0 + wm + i * 16 + quad * 4;
      #pragma unroll
      for (int r = 0; r < 4; r++) {
        float v = acc[i][j][r] + bj;
        if (relu) v = fmaxf(v, 0.0f);
        C[(size_t)(row + r) * N + col] = f2bf(v);
      }
    }
  }
}

// ---------------- persistent GRU scan (fence-free LLC protocol) --------------
// 256 WGs (1/CU). WG = (bb,jb): bb owns 64 batches, jb owns 16 cols x 3 gates.
// W_hh slice (96KB) + starts bitmask in LDS once. h fp32 in registers.
// Cross-WG h exchange goes ONLY through agent-scope RELAXED atomics (LLC is
// the coherence point): stores are write-through (no dirty L2 -> no wbl2),
// loads always fetch from LLC (no invalidate). Flag barrier: per-wave
// s_waitcnt drain + __syncthreads, then relaxed flag store; 64-lane poll.
__global__ __launch_bounds__(256, 1) void gru_scan(
    const unsigned short* __restrict__ xg,   // chunk-local [B][Tc][3H]
    const int* __restrict__ starts,
    const unsigned short* __restrict__ Whh,
    const unsigned short* __restrict__ bhh,
    float* __restrict__ hf,                  // [B][H] fp32 master
    unsigned long long* __restrict__ hb0,    // bf16 mirror ping (8B units)
    unsigned long long* __restrict__ hb1,    // bf16 mirror pong
    unsigned short* __restrict__ hall,       // [B][Tc][H] bf16
    int t0, int Tc,
    int* __restrict__ flags)                 // [NWG_] step flags, 128B stride
{
  __shared__ short Ws[3 * 16 * 1032];   // 99 KB: [g][jj][k] stride 1032
  __shared__ short Hs[64 * 136];        // 17 KB: [row][k-chunk 128] stride 136
  __shared__ unsigned sbits[64][4];     // starts bitmask: 64 rows x 128 bits
  const int tid  = threadIdx.x;
  const int wg   = blockIdx.x;
  const int jb   = wg & 63, bb = wg >> 6;
  const int j0   = jb * 16, b0 = bb * 64;
  const int wave = tid >> 6, lane = tid & 63;
  const int quad = lane >> 4, l15 = lane & 15;

  // one-time: W_hh slice -> LDS (48 rows x 1024 k)
  for (int c = tid; c < 48 * 128; c += 256) {
    const int row = c >> 7;          // g*16 + jj
    const int kc  = (c & 127) * 8;
    const int g = row >> 4, jj = row & 15;
    *(uint4*)&Ws[row * 1032 + kc] =
        *(const uint4*)(Whh + (size_t)(g * H_ + j0 + jj) * H_ + kc);
  }
  // one-time: starts -> bitmask
  for (int c = tid; c < 64 * 4; c += 256) {
    const int row = c >> 2, w = c & 3;
    unsigned m = 0;
    #pragma unroll
    for (int bi = 0; bi < 32; bi++)
      m |= (starts[(b0 + row) * T_ + w * 32 + bi] ? 1u : 0u) << bi;
    sbits[row][w] = m;
  }
  const float br = bf2f(bhh[j0 + l15]);
  const float bz = bf2f(bhh[H_ + j0 + l15]);
  const float bn = bf2f(bhh[2 * H_ + j0 + l15]);
  const int col = j0 + l15;

  // register-resident fp32 h: 4 owned slots (rows r0..r0+3, col)
  const int r0 = wave * 16 + quad * 4;
  float hreg[4];
  #pragma unroll
  for (int r = 0; r < 4; r++)
    hreg[r] = hf[(size_t)(b0 + r0 + r) * H_ + col];

  __syncthreads();  // Ws / sbits ready

  for (int tl = 0; tl < Tc; tl++) {
    const int t = t0 + tl;
    const unsigned long long* hin = (t & 1) ? hb1 : hb0;
    unsigned* hout_u = (unsigned*)((t & 1) ? hb0 : hb1);

    // prefetch this step's xg values (12 scalar loads, consumed in epilogue)
    float xr[4], xz[4], xnv[4];
    #pragma unroll
    for (int r = 0; r < 4; r++) {
      const size_t xrow = ((size_t)(b0 + r0 + r) * Tc + tl) * (3 * H_);
      xr[r]  = bf2f(xg[xrow + col]);
      xz[r]  = bf2f(xg[xrow + H_ + col]);
      xnv[r] = bf2f(xg[xrow + 2 * H_ + col]);
    }

    // prefetch Hs chunk 0 via agent-scope atomic loads (fresh from LLC)
    unsigned long long pf[8];
    #pragma unroll
    for (int u = 0; u < 8; u++) {
      const int c = tid + u * 256;             // [0,2048)
      const int row = c >> 5, kc = (c & 31) * 4;
      pf[u] = __hip_atomic_load(
          &hin[(((size_t)(b0 + row)) * H_ + kc) >> 2],
          __ATOMIC_RELAXED, __HIP_MEMORY_SCOPE_AGENT);
    }

    f32x4 acc[3] = {};
    const unsigned tw = (unsigned)(t >> 5), tb = (unsigned)(t & 31);
    for (int kc0 = 0; kc0 < H_; kc0 += 128) {
      __syncthreads();  // Hs consumed by previous iteration's MFMA
      #pragma unroll
      for (int u = 0; u < 8; u++) {
        const int c = tid + u * 256;
        const int row = c >> 5, kc = (c & 31) * 4;
        unsigned long long v = pf[u];
        if ((sbits[row][tw] >> tb) & 1u) v = 0ull;
        *(unsigned long long*)&Hs[row * 136 + kc] = v;
      }
      __syncthreads();
      if (kc0 + 128 < H_) {
        #pragma unroll
        for (int u = 0; u < 8; u++) {
          const int c = tid + u * 256;
          const int row = c >> 5, kc = (c & 31) * 4;
          pf[u] = __hip_atomic_load(
              &hin[(((size_t)(b0 + row)) * H_ + kc0 + 128 + kc) >> 2],
              __ATOMIC_RELAXED, __HIP_MEMORY_SCOPE_AGENT);
        }
      }
      #pragma unroll
      for (int kk = 0; kk < 128; kk += 32) {
        bf16x8 a = *(const bf16x8*)&Hs[(wave * 16 + l15) * 136 + kk + quad * 8];
        #pragma unroll
        for (int g = 0; g < 3; g++) {
          bf16x8 b = *(const bf16x8*)&Ws[(g * 16 + l15) * 1032 + kc0 + kk + quad * 8];
          acc[g] = __builtin_amdgcn_mfma_f32_16x16x32_bf16(a, b, acc[g], 0, 0, 0);
        }
      }
    }

    // epilogue: gate math in registers; pack col pairs; atomic store to LLC
    #pragma unroll
    for (int r = 0; r < 4; r++) {
      const int lrow = r0 + r;
      const int b = b0 + lrow;
      const float kb = ((sbits[lrow][tw] >> tb) & 1u) ? 0.0f : 1.0f;
      const float hr = acc[0][r] + br;
      const float hz = acc[1][r] + bz;
      const float hn = acc[2][r] + bn;
      const float rg = 1.0f / (1.0f + __expf(-(xr[r] + hr)));
      const float zg = 1.0f / (1.0f + __expf(-(xz[r] + hz)));
      const float ng = tanhf(xnv[r] + rg * hn);
      const float hv = (1.0f - zg) * ng + zg * (hreg[r] * kb);
      hreg[r] = hv;
      const unsigned mine = (unsigned)f2bf(hv);
      const unsigned other = (unsigned)__shfl_xor((int)mine, 1, 64);
      if ((l15 & 1) == 0) {
        const unsigned packed = mine | (other << 16);
        __hip_atomic_store(&hout_u[((size_t)b * H_ + col) >> 1], packed,
                           __ATOMIC_RELAXED, __HIP_MEMORY_SCOPE_AGENT);
        ((unsigned*)hall)[(((size_t)b * Tc + tl) * H_ + col) >> 1] = packed;
      }
    }

    // fence-free barrier: drain own stores, join, store flag, poll group
    const int my = t0 + tl + 1;
    __builtin_amdgcn_s_waitcnt(0);  // this wave's atomic stores reached LLC
    __syncthreads();                // all 4 waves drained
    if (tid == 0)
      __hip_atomic_store(&flags[wg * 32], my, __ATOMIC_RELAXED,
                         __HIP_MEMORY_SCOPE_AGENT);
    if (tid < 64) {
      while (__hip_atomic_load(&flags[(bb * 64 + tid) * 32], __ATOMIC_RELAXED,
                               __HIP_MEMORY_SCOPE_AGENT) < my)
        __builtin_amdgcn_s_sleep(1);
    }
    __syncthreads();
  }

  // write back register h to fp32 master (read by next dispatch / hfin_store)
  #pragma unroll
  for (int r = 0; r < 4; r++)
    hf[(size_t)(b0 + r0 + r) * H_ + col] = hreg[r];
}

// ------------- heads: means & log_std fused (N=64), dual-dtype store ---------
__global__ __launch_bounds__(256) void heads_kernel(
    const unsigned short* __restrict__ feats,
    const unsigned short* __restrict__ Wm, const unsigned short* __restrict__ bm,
    const unsigned short* __restrict__ Wl, const unsigned short* __restrict__ bl,
    void* __restrict__ outbuf, int t0, int tcShift, const int* __restrict__ flag)
{
  __shared__ short Fs[64][40];
  __shared__ short Ws[64][40];
  const int fl = *flag;
  const int tid  = threadIdx.x;
  const int wave = tid >> 6, lane = tid & 63;
  const int quad = lane >> 4, l15 = lane & 15;
  const int m0 = blockIdx.x * 64;
  const int lrow = tid >> 2, lk = (tid & 3) * 8;
  f32x4 acc[4] = {};
  for (int k0 = 0; k0 < H_; k0 += 32) {
    __syncthreads();
    *(uint4*)&Fs[lrow][lk] = *(const uint4*)(feats + (size_t)(m0 + lrow) * H_ + k0 + lk);
    const unsigned short* wsrc = (lrow < 32)
        ? (Wm + (size_t)lrow * H_ + k0 + lk)
        : (Wl + (size_t)(lrow - 32) * H_ + k0 + lk);
    *(uint4*)&Ws[lrow][lk] = *(const uint4*)wsrc;
    __syncthreads();
    bf16x8 af = *(const bf16x8*)&Fs[wave * 16 + l15][quad * 8];
    #pragma unroll
    for (int j = 0; j < 4; j++) {
      bf16x8 bfv = *(const bf16x8*)&Ws[j * 16 + l15][quad * 8];
      acc[j] = __builtin_amdgcn_mfma_f32_16x16x32_bf16(af, bfv, acc[j], 0, 0, 0);
    }
  }
  const int tcMask = (1 << tcShift) - 1;
  const size_t lstdBase = (size_t)B_ * T_ * A_;
  #pragma unroll
  for (int j = 0; j < 4; j++) {
    const int col = j * 16 + l15;
    #pragma unroll
    for (int r = 0; r < 4; r++) {
      const int row = m0 + wave * 16 + quad * 4 + r;  // chunk-local
      const int grow = (row >> tcShift) * T_ + t0 + (row & tcMask);
      float v = acc[j][r];
      size_t idx;
      if (col < 32) {
        v += bf2f(bm[col]);
        idx = (size_t)grow * A_ + col;
      } else {
        v += bf2f(bl[col - 32]);
        v = fminf(fmaxf(v, -20.0f), 2.0f);
        idx = lstdBase + (size_t)grow * A_ + (col - 32);
      }
      if (fl) ((float*)outbuf)[idx] = v;
      else    ((unsigned short*)outbuf)[idx] = f2bf(v);
    }
  }
}

__global__ __launch_bounds__(256) void h0_cast(const void* __restrict__ h0,
                                               float* __restrict__ hf,
                                               unsigned short* __restrict__ hb0,
                                               const int* __restrict__ flag) {
  const int fl = *flag;
  int i = blockIdx.x * 256 + threadIdx.x;
  float v = fl ? ((const float*)h0)[i] : bf2f(((const unsigned short*)h0)[i]);
  hf[i] = v;
  hb0[i] = f2bf(v);
}
__global__ __launch_bounds__(256) void hfin_store(const float* __restrict__ h,
                                                  void* __restrict__ outbuf,
                                                  const int* __restrict__ flag) {
  const int fl = *flag;
  const size_t base = 2ull * B_ * T_ * A_;
  int i = blockIdx.x * 256 + threadIdx.x;
  if (fl) ((float*)outbuf)[base + i] = h[i];
  else    ((unsigned short*)outbuf)[base + i] = f2bf(h[i]);
}

extern "C" void kernel_launch(void* const* d_in, const int* in_sizes, int n_in,
                              void* d_out, int out_size, void* d_ws, size_t ws_size,
                              hipStream_t stream)
{
  const void* obs    = d_in[0];
  const void* h0in   = d_in[1];
  const int*  starts = (const int*)d_in[2];
  const void* fsrc[14] = { d_in[5], d_in[7], d_in[9], d_in[11], d_in[13], d_in[15],
                           d_in[3], d_in[4], d_in[6], d_in[8], d_in[10], d_in[12],
                           d_in[14], d_in[16] };
  const int fn[14] = { FC_ * D_, 3 * H_ * FC_, 3 * H_ * H_, H_ * H_, A_ * H_, A_ * H_,
                       D_, D_, FC_, 3 * H_, 3 * H_, H_, A_, A_ };

  char* ws = (char*)d_ws;
  int* flag = (int*)ws;
  size_t cur = 256;
  unsigned short* cdst[14];
  for (int i = 0; i < 14; i++) {
    cdst[i] = (unsigned short*)(ws + cur);
    cur += (size_t)fn[i] * 2;
    cur = (cur + 255) & ~255ull;
  }
  const size_t chunkBase = cur;
  const size_t fixedTail = 1048576ull /*hf*/ + 2ull * 524288ull /*hb0/1*/
                         + 32768ull /*flags*/;

  // Pick largest Tc with: chunkBase + Tc*2883584 + fixedTail <= ws_size
  int Tc = 1;
  for (int c = 32; c >= 1; c >>= 1) {
    size_t need = chunkBase + (size_t)c * 2883584ull + fixedTail;
    if (need <= ws_size) { Tc = c; break; }
  }
  int tcShift = 0;
  while ((1 << tcShift) < Tc) tcShift++;

  unsigned short* xn   = (unsigned short*)(ws + chunkBase);
  unsigned short* xfc  = (unsigned short*)(ws + chunkBase + (size_t)Tc * 262144ull);
  unsigned short* xg   = (unsigned short*)(ws + chunkBase + (size_t)Tc * 786432ull);
  unsigned short* hall = (unsigned short*)(ws + chunkBase + (size_t)Tc * 2359296ull);
  size_t o = chunkBase + (size_t)Tc * 2883584ull;
  float* hf           = (float*)(ws + o);           o += 1048576ull;
  unsigned short* hb0 = (unsigned short*)(ws + o);  o += 524288ull;
  unsigned short* hb1 = (unsigned short*)(ws + o);  o += 524288ull;
  int* flags          = (int*)(ws + o);             // NWG_ x 128B
  unsigned short* feats = xg;  // xg dead once the chunk's scan is done

  const unsigned short *Wfc = cdst[0], *Wih = cdst[1], *Whh = cdst[2], *Wout = cdst[3];
  const unsigned short *Wmean = cdst[4], *Wls = cdst[5];
  const unsigned short *gam = cdst[6], *bet = cdst[7], *bfc = cdst[8], *bih = cdst[9];
  const unsigned short *bhh = cdst[10], *bout = cdst[11], *bmean = cdst[12], *bls = cdst[13];

  detect_kernel<<<dim3(1), dim3(256), 0, stream>>>((const unsigned short*)obs, flag);
  CanonArgs ca;
  int total = 0;
  for (int i = 0; i < 14; i++) {
    ca.src[i] = fsrc[i];
    ca.dst[i] = cdst[i];
    ca.ofs[i] = total;
    total += fn[i];
  }
  ca.ofs[14] = total;
  canon_kernel<<<dim3((total / 8 + 255) / 256), dim3(256), 0, stream>>>(ca, flag);
  h0_cast<<<dim3(B_ * H_ / 256), dim3(256), 0, stream>>>(h0in, hf, hb0, flag);
  hipMemsetAsync(flags, 0, 32768, stream);

  const int Mc = B_ * Tc;
  for (int t0 = 0; t0 < T_; t0 += Tc) {
    ln_kernel<<<dim3(Mc / 4), dim3(256), 0, stream>>>(obs, gam, bet, xn, t0, tcShift, flag);
    gemm_tn<<<dim3(FC_ / 128, Mc / 128), dim3(256), 0, stream>>>(
        xn, Wfc, bfc, xfc, Mc, FC_, D_, 1);
    gemm_tn<<<dim3(3 * H_ / 128, Mc / 128), dim3(256), 0, stream>>>(
        xfc, Wih, bih, xg, Mc, 3 * H_, FC_, 0);

    gru_scan<<<dim3(NWG_), dim3(256), 0, stream>>>(
        xg, starts, Whh, bhh, hf,
        (unsigned long long*)hb0, (unsigned long long*)hb1,
        hall, t0, Tc, flags);

    gemm_tn<<<dim3(H_ / 128, Mc / 128), dim3(256), 0, stream>>>(
        hall, Wout, bout, feats, Mc, H_, H_, 1);
    heads_kernel<<<dim3(Mc / 64), dim3(256), 0, stream>>>(
        feats, Wmean, bmean, Wls, bls, d_out, t0, tcShift, flag);
  }

  hfin_store<<<dim3(B_ * H_ / 256), dim3(256), 0, stream>>>(hf, d_out, flag);
}